// Round 5
// baseline (301.100 us; speedup 1.0000x reference)
//
#include <hip/hip_runtime.h>
#include <hip/hip_bf16.h>
#include <hip/hip_cooperative_groups.h>

namespace cg = cooperative_groups;

#define C 256
#define C2 128
#define NTOK 10368
#define NCHUNK 36            // 36 * 288 = 10368
#define KSTEPS 9             // 288 / 32
#define NTILE32 324          // 324 * 32 = 10368
#define GRID 512

typedef __bf16 bf16x8 __attribute__((ext_vector_type(8)));
typedef float  f32x4  __attribute__((ext_vector_type(4)));

// ws layout (float offsets)
#define WS_Q      0                       // 256
#define WS_PT     256                     // 32768 float-slots = 65536 bf16
#define WS_SPART  33024                   // 324*256 = 82944
#define WS_FEATB  115968                  // 2,654,208 bf16 = 1,327,104 slots
#define WS_FEATT  1443072                 // 1,327,104 slots
#define WS_GPART  2770176                 // 36 * 65536 = 2,359,296

__device__ __constant__ int TRI_I[10] = {0,0,0,0,1,1,1,2,2,3};
__device__ __constant__ int TRI_J[10] = {0,1,2,3,1,2,3,2,3,3};

// One cooperative kernel, 4 phases separated by grid.sync():
//  P1 prep : featB[c][n]=bf16(feat), featT[n][c]=bf16(feat), sPart (324 blocks)
//  P2 gram : upper-tri 64x64 tiles of featB@featB^T per 288-col chunk (360 blocks)
//  P3 mid  : G-reduce -> M -> Pt (+identity on diag) , q   (256 blocks)
//  P4 final: out[c,n] = q[c] + sum_k Pt'[c,k] featT[n,k]   (324 blocks)
__global__ __launch_bounds__(256, 2) void k_mega(const float* __restrict__ feat,
                                                 const float* __restrict__ Wi,
                                                 const float* __restrict__ bi,
                                                 const float* __restrict__ Wj,
                                                 const float* __restrict__ bj,
                                                 float* __restrict__ out,
                                                 __bf16* __restrict__ featB,
                                                 __bf16* __restrict__ featT,
                                                 float* __restrict__ sPart,
                                                 float* __restrict__ Gpart,
                                                 __bf16* __restrict__ Pt,
                                                 float* __restrict__ q) {
    cg::grid_group grid = cg::this_grid();
    __shared__ __align__(16) char smem[16384];

    const int bid = blockIdx.x;
    const int t = threadIdx.x;
    const int wave = t >> 6, lane = t & 63;
    const int l15 = lane & 15, lq = lane >> 4;

    // ---------------- Phase 1: prep ----------------
    if (bid < NTILE32) {
        ushort (*Ls)[C] = (ushort (*)[C])smem;
        int n0 = bid * 32;
        int c = t;

        float vals[32];
        float ssum = 0.f;
#pragma unroll
        for (int i = 0; i < 8; ++i) {
            float4 v = *(const float4*)(feat + (size_t)c * NTOK + n0 + i * 4);
            vals[i * 4 + 0] = v.x; vals[i * 4 + 1] = v.y;
            vals[i * 4 + 2] = v.z; vals[i * 4 + 3] = v.w;
            ssum += v.x + v.y + v.z + v.w;
        }
        sPart[bid * C + c] = ssum;

        ushort tmp[32];
#pragma unroll
        for (int n = 0; n < 32; ++n) {
            __bf16 b = (__bf16)vals[n];
            tmp[n] = *(ushort*)&b;
            Ls[n][c] = tmp[n];
        }
        uint4* bdst = (uint4*)(featB + (size_t)c * NTOK + n0);
#pragma unroll
        for (int i = 0; i < 4; ++i) bdst[i] = ((const uint4*)tmp)[i];

        __syncthreads();
        int n = t >> 3;
        int koff = (t & 7) * 32;
        const uint4* src = (const uint4*)&Ls[n][koff];
        uint4* dst = (uint4*)(featT + (size_t)(n0 + n) * C + koff);
#pragma unroll
        for (int i = 0; i < 4; ++i) dst[i] = src[i];
    }
    grid.sync();

    // ---------------- Phase 2: gram ----------------
    if (bid < 10 * NCHUNK) {
        int tri = bid / NCHUNK, nc = bid - tri * NCHUNK;
        int it = TRI_I[tri], jt = TRI_J[tri];

        int i_row = it * 64 + wave * 16 + l15;
        const __bf16* fA = featB + (size_t)i_row * NTOK;
        int nbase = nc * (KSTEPS * 32);

        f32x4 acc[4];
#pragma unroll
        for (int f = 0; f < 4; ++f) acc[f] = (f32x4){0.f, 0.f, 0.f, 0.f};

#pragma unroll
        for (int ks = 0; ks < KSTEPS; ++ks) {
            int n0 = nbase + ks * 32 + lq * 8;
            bf16x8 afrag = *(const bf16x8*)(fA + n0);
#pragma unroll
            for (int f = 0; f < 4; ++f) {
                bf16x8 bfrag = *(const bf16x8*)(featB + (size_t)(jt * 64 + f * 16 + l15) * NTOK + n0);
                acc[f] = __builtin_amdgcn_mfma_f32_16x16x32_bf16(afrag, bfrag, acc[f], 0, 0, 0);
            }
        }

        float* Gp = Gpart + (size_t)nc * (C * C);
        int gib = it * 64 + wave * 16 + lq * 4;
#pragma unroll
        for (int f = 0; f < 4; ++f) {
            int gj = jt * 64 + f * 16 + l15;
#pragma unroll
            for (int r = 0; r < 4; ++r) Gp[(gib + r) * C + gj] = acc[f][r];
            if (it != jt) {
                float4 v = make_float4(acc[f][0], acc[f][1], acc[f][2], acc[f][3]);
                *(float4*)(Gp + (size_t)gj * C + gib) = v;
            }
        }
    }
    grid.sync();

    // ---------------- Phase 3: mid ----------------
    if (bid < C) {
        float* Gcol  = (float*)smem;        // 256
        float* Mpart = Gcol + C;            // 256
        float* Mcol  = Mpart + C;           // 128
        float* sred  = Mcol + C2;           // 8
        int c = bid;

        float g = 0.f;
        const float* gp = Gpart + (size_t)c * C + t;
#pragma unroll 4
        for (int p = 0; p < NCHUNK; ++p) g += gp[(size_t)p * (C * C)];
        Gcol[t] = g;

        float sv = 0.f;
        for (int p = t; p < NTILE32; p += 256) sv += sPart[p * C + c];
        for (int off = 32; off > 0; off >>= 1) sv += __shfl_xor(sv, off);
        if ((t & 63) == 0) sred[t >> 6] = sv;
        __syncthreads();
        float s_c = sred[0] + sred[1] + sred[2] + sred[3];

        int m = t & 127, h = t >> 7;
        float a = 0.f;
#pragma unroll 8
        for (int k0 = h * 128; k0 < h * 128 + 128; k0 += 4) {
            float4 w = *(const float4*)(Wj + m * C + k0);
            a += w.x * Gcol[k0] + w.y * Gcol[k0 + 1] + w.z * Gcol[k0 + 2] + w.w * Gcol[k0 + 3];
        }
        Mpart[t] = a;
        __syncthreads();
        if (t < C2) Mcol[t] = Mpart[t] + Mpart[t + 128] + bj[t] * s_c;
        __syncthreads();

        float acc = 0.f;
#pragma unroll 8
        for (int mm = 0; mm < C2; ++mm) acc += Wi[mm * C + t] * Mcol[mm];
        // identity fold: out = (P + I) @ featT^T + q  -> residual comes free via MFMA
        float pv = acc * (1.0f / NTOK) + ((t == c) ? 1.0f : 0.0f);
        Pt[(size_t)c * C + t] = (__bf16)pv;

        float qv = (t < C2) ? bi[t] * Mcol[t] : 0.f;
        for (int off = 32; off > 0; off >>= 1) qv += __shfl_xor(qv, off);
        if ((t & 63) == 0) sred[4 + (t >> 6)] = qv;
        __syncthreads();
        if (t == 0) q[c] = (sred[4] + sred[5] + sred[6] + sred[7]) * (1.0f / NTOK);
    }
    grid.sync();

    // ---------------- Phase 4: final ----------------
    if (bid < NTILE32) {
        int n0 = bid * 32;

        f32x4 acc[4][2];
#pragma unroll
        for (int si = 0; si < 4; ++si)
#pragma unroll
            for (int ns = 0; ns < 2; ++ns) acc[si][ns] = (f32x4){0.f, 0.f, 0.f, 0.f};

#pragma unroll
        for (int ks = 0; ks < 8; ++ks) {
            int k0 = ks * 32;
            bf16x8 b[2];
#pragma unroll
            for (int ns = 0; ns < 2; ++ns)
                b[ns] = *(const bf16x8*)(featT + (size_t)(n0 + ns * 16 + l15) * C + k0 + lq * 8);
#pragma unroll
            for (int si = 0; si < 4; ++si) {
                int crow = wave * 64 + si * 16 + l15;
                bf16x8 a = *(const bf16x8*)(Pt + (size_t)crow * C + k0 + lq * 8);
#pragma unroll
                for (int ns = 0; ns < 2; ++ns)
                    acc[si][ns] = __builtin_amdgcn_mfma_f32_16x16x32_bf16(a, b[ns], acc[si][ns], 0, 0, 0);
            }
        }

#pragma unroll
        for (int si = 0; si < 4; ++si)
#pragma unroll
            for (int ns = 0; ns < 2; ++ns)
#pragma unroll
                for (int r = 0; r < 4; ++r) {
                    int c = wave * 64 + si * 16 + lq * 4 + r;
                    int n = n0 + ns * 16 + l15;
                    out[(size_t)c * NTOK + n] = q[c] + acc[si][ns][r];
                }
    }
}

extern "C" void kernel_launch(void* const* d_in, const int* in_sizes, int n_in,
                              void* d_out, int out_size, void* d_ws, size_t ws_size,
                              hipStream_t stream) {
    const float* feat = (const float*)d_in[0];
    const float* Wi   = (const float*)d_in[1];
    const float* bi   = (const float*)d_in[2];
    const float* Wj   = (const float*)d_in[3];
    const float* bj   = (const float*)d_in[4];
    float* out = (float*)d_out;

    float* ws = (float*)d_ws;
    float*  q     = ws + WS_Q;
    __bf16* Pt    = (__bf16*)(ws + WS_PT);
    float*  sPart = ws + WS_SPART;
    __bf16* featB = (__bf16*)(ws + WS_FEATB);
    __bf16* featT = (__bf16*)(ws + WS_FEATT);
    float*  Gpart = ws + WS_GPART;

    void* args[] = {(void*)&feat, (void*)&Wi, (void*)&bi, (void*)&Wj, (void*)&bj,
                    (void*)&out, (void*)&featB, (void*)&featT, (void*)&sPart,
                    (void*)&Gpart, (void*)&Pt, (void*)&q};
    hipLaunchCooperativeKernel((void*)k_mega, dim3(GRID), dim3(256), args, 0, stream);
}

// Round 6
// 120.139 us; speedup vs baseline: 2.5063x; 2.5063x over previous
//
#include <hip/hip_runtime.h>
#include <hip/hip_bf16.h>

#define C 256
#define C2 128
#define NTOK 10368
#define NCHUNK 36            // 36 * 288 = 10368
#define KSTEPS 9             // 288 / 32
#define NTILE32 324          // 324 * 32 = 10368

typedef __bf16 bf16x8 __attribute__((ext_vector_type(8)));
typedef float  f32x4  __attribute__((ext_vector_type(4)));

// ws layout (float offsets)
#define WS_Q      0                       // 256
#define WS_PT     256                     // 32768 float-slots = 65536 bf16
#define WS_SPART  33024                   // 324*256 = 82944
#define WS_FEATB  115968                  // 2,654,208 bf16 = 1,327,104 slots
#define WS_FEATT  1443072                 // 1,327,104 slots
#define WS_GPART  2770176                 // 36 * 65536 = 2,359,296
// total ~5.13M floats = 20.5 MB

__device__ __constant__ int TRI_I[10] = {0,0,0,0,1,1,1,2,2,3};
__device__ __constant__ int TRI_J[10] = {0,1,2,3,1,2,3,2,3,3};

// ---------- k_prep: featB[c][n]=bf16(feat), featT[n][c]=bf16(feat), sPart ----------
// grid 324 (n-tile 32), 256 threads (thread = row c)
__global__ __launch_bounds__(256) void k_prep(const float* __restrict__ feat,
                                              __bf16* __restrict__ featB,
                                              __bf16* __restrict__ featT,
                                              float* __restrict__ sPart) {
    __shared__ __align__(16) ushort Ls[32][C];
    int n0 = blockIdx.x * 32;
    int c = threadIdx.x;

    float vals[32];
    float ssum = 0.f;
#pragma unroll
    for (int i = 0; i < 8; ++i) {
        float4 v = *(const float4*)(feat + (size_t)c * NTOK + n0 + i * 4);
        vals[i * 4 + 0] = v.x; vals[i * 4 + 1] = v.y;
        vals[i * 4 + 2] = v.z; vals[i * 4 + 3] = v.w;
        ssum += v.x + v.y + v.z + v.w;
    }
    sPart[blockIdx.x * C + c] = ssum;

    ushort tmp[32];
#pragma unroll
    for (int n = 0; n < 32; ++n) {
        __bf16 b = (__bf16)vals[n];
        tmp[n] = *(ushort*)&b;
        Ls[n][c] = tmp[n];
    }
    // c-major bf16 (coalesced 16B stores per thread row)
    uint4* bdst = (uint4*)(featB + (size_t)c * NTOK + n0);
#pragma unroll
    for (int i = 0; i < 4; ++i) bdst[i] = ((const uint4*)tmp)[i];

    __syncthreads();
    // n-major bf16 via LDS transpose
    int n = threadIdx.x >> 3;
    int koff = (threadIdx.x & 7) * 32;
    const uint4* src = (const uint4*)&Ls[n][koff];
    uint4* dst = (uint4*)(featT + (size_t)(n0 + n) * C + koff);
#pragma unroll
    for (int i = 0; i < 4; ++i) dst[i] = src[i];
}

// ---------- k_gram: upper-triangle 64x64 tiles of feat@feat^T per 288-col chunk ----------
// grid (10, 36); pure global bf16x8 loads + MFMA, no packing
__global__ __launch_bounds__(256) void k_gram(const __bf16* __restrict__ featB,
                                              float* __restrict__ Gpart) {
    int it = TRI_I[blockIdx.x], jt = TRI_J[blockIdx.x];
    int nc = blockIdx.y;
    int tid = threadIdx.x;
    int wave = tid >> 6, lane = tid & 63;
    int l15 = lane & 15, lq = lane >> 4;

    int i_row = it * 64 + wave * 16 + l15;
    const __bf16* fA = featB + (size_t)i_row * NTOK;
    int nbase = nc * (KSTEPS * 32);

    f32x4 acc[4];
#pragma unroll
    for (int f = 0; f < 4; ++f) acc[f] = (f32x4){0.f, 0.f, 0.f, 0.f};

#pragma unroll
    for (int ks = 0; ks < KSTEPS; ++ks) {
        int n0 = nbase + ks * 32 + lq * 8;
        bf16x8 afrag = *(const bf16x8*)(fA + n0);
#pragma unroll
        for (int f = 0; f < 4; ++f) {
            bf16x8 bfrag = *(const bf16x8*)(featB + (size_t)(jt * 64 + f * 16 + l15) * NTOK + n0);
            acc[f] = __builtin_amdgcn_mfma_f32_16x16x32_bf16(afrag, bfrag, acc[f], 0, 0, 0);
        }
    }

    float* Gp = Gpart + (size_t)nc * (C * C);
    int gib = it * 64 + wave * 16 + lq * 4;
#pragma unroll
    for (int f = 0; f < 4; ++f) {
        int gj = jt * 64 + f * 16 + l15;
#pragma unroll
        for (int r = 0; r < 4; ++r) Gp[(gib + r) * C + gj] = acc[f][r];
        if (it != jt) {
            float4 v = make_float4(acc[f][0], acc[f][1], acc[f][2], acc[f][3]);
            *(float4*)(Gp + (size_t)gj * C + gib) = v;   // mirrored (G symmetric)
        }
    }
}

// ---------- k_mid: per-column fused  G-reduce -> M[:,c] -> Pt[c,:] (+I), q[c] ----------
// grid 256 (block = column c), 256 threads
__global__ __launch_bounds__(256) void k_mid(const float* __restrict__ Gpart,
                                             const float* __restrict__ sPart,
                                             const float* __restrict__ Wi,
                                             const float* __restrict__ bi,
                                             const float* __restrict__ Wj,
                                             const float* __restrict__ bj,
                                             __bf16* __restrict__ Pt,
                                             float* __restrict__ q) {
    __shared__ float Gcol[C];
    __shared__ float Mpart[C];
    __shared__ float Mcol[C2];
    __shared__ float sred[8];
    int c = blockIdx.x, t = threadIdx.x;

    // G column c == row c (symmetry): coalesced reduction over chunk partials
    float g = 0.f;
    const float* gp = Gpart + (size_t)c * C + t;
#pragma unroll 4
    for (int p = 0; p < NCHUNK; ++p) g += gp[(size_t)p * (C * C)];
    Gcol[t] = g;

    // s[c] = total row sum
    float sv = 0.f;
    for (int p = t; p < NTILE32; p += 256) sv += sPart[p * C + c];
    for (int off = 32; off > 0; off >>= 1) sv += __shfl_xor(sv, off);
    if ((t & 63) == 0) sred[t >> 6] = sv;
    __syncthreads();
    float s_c = sred[0] + sred[1] + sred[2] + sred[3];

    // M[m,c] = Wj[m,:].Gcol + bj[m]*s_c   (split k-range across thread halves)
    int m = t & 127, h = t >> 7;
    float a = 0.f;
#pragma unroll 8
    for (int k0 = h * 128; k0 < h * 128 + 128; k0 += 4) {
        float4 w = *(const float4*)(Wj + m * C + k0);
        a += w.x * Gcol[k0] + w.y * Gcol[k0 + 1] + w.z * Gcol[k0 + 2] + w.w * Gcol[k0 + 3];
    }
    Mpart[t] = a;
    __syncthreads();
    if (t < C2) Mcol[t] = Mpart[t] + Mpart[t + 128] + bj[t] * s_c;
    __syncthreads();

    // Pt[c,k] = (Wi[:,k].Mcol)/N + I[c,k]  (identity fold: residual via MFMA), q[c] = (bi.Mcol)/N
    float acc = 0.f;
#pragma unroll 8
    for (int mm = 0; mm < C2; ++mm) acc += Wi[mm * C + t] * Mcol[mm];
    float pv = acc * (1.0f / NTOK) + ((t == c) ? 1.0f : 0.0f);
    Pt[(size_t)c * C + t] = (__bf16)pv;

    float qv = (t < C2) ? bi[t] * Mcol[t] : 0.f;
    for (int off = 32; off > 0; off >>= 1) qv += __shfl_xor(qv, off);
    if ((t & 63) == 0) sred[4 + (t >> 6)] = qv;
    __syncthreads();
    if (t == 0) q[c] = (sred[4] + sred[5] + sred[6] + sred[7]) * (1.0f / NTOK);
}

// ---------- k_final: out[c,n] = q[c] + sum_k Pt'[c,k] featT[n,k]  (residual folded into Pt') ----------
// grid (324, 2); no LDS, no barriers, no residual stream
__global__ __launch_bounds__(256) void k_final(const __bf16* __restrict__ featT,
                                               const __bf16* __restrict__ Pt,
                                               const float* __restrict__ q,
                                               float* __restrict__ out) {
    int n0 = blockIdx.x * 32;
    int cbase = blockIdx.y * 128;
    int tid = threadIdx.x;
    int wave = tid >> 6, lane = tid & 63;
    int l15 = lane & 15, lq = lane >> 4;

    f32x4 acc[2][2];
#pragma unroll
    for (int si = 0; si < 2; ++si)
#pragma unroll
        for (int ns = 0; ns < 2; ++ns) acc[si][ns] = (f32x4){0.f, 0.f, 0.f, 0.f};

#pragma unroll
    for (int ks = 0; ks < 8; ++ks) {
        int k0 = ks * 32;
        bf16x8 b[2];
#pragma unroll
        for (int ns = 0; ns < 2; ++ns)
            b[ns] = *(const bf16x8*)(featT + (size_t)(n0 + ns * 16 + l15) * C + k0 + lq * 8);
#pragma unroll
        for (int si = 0; si < 2; ++si) {
            int crow = cbase + wave * 32 + si * 16 + l15;
            bf16x8 a = *(const bf16x8*)(Pt + (size_t)crow * C + k0 + lq * 8);
#pragma unroll
            for (int ns = 0; ns < 2; ++ns)
                acc[si][ns] = __builtin_amdgcn_mfma_f32_16x16x32_bf16(a, b[ns], acc[si][ns], 0, 0, 0);
        }
    }

#pragma unroll
    for (int si = 0; si < 2; ++si)
#pragma unroll
        for (int ns = 0; ns < 2; ++ns)
#pragma unroll
            for (int r = 0; r < 4; ++r) {
                int c = cbase + wave * 32 + si * 16 + lq * 4 + r;
                int n = n0 + ns * 16 + l15;
                out[(size_t)c * NTOK + n] = q[c] + acc[si][ns][r];
            }
}

extern "C" void kernel_launch(void* const* d_in, const int* in_sizes, int n_in,
                              void* d_out, int out_size, void* d_ws, size_t ws_size,
                              hipStream_t stream) {
    const float* feat = (const float*)d_in[0];
    const float* Wi   = (const float*)d_in[1];
    const float* bi   = (const float*)d_in[2];
    const float* Wj   = (const float*)d_in[3];
    const float* bj   = (const float*)d_in[4];
    float* out = (float*)d_out;

    float* ws = (float*)d_ws;
    float*  q     = ws + WS_Q;
    __bf16* Pt    = (__bf16*)(ws + WS_PT);
    float*  sPart = ws + WS_SPART;
    __bf16* featB = (__bf16*)(ws + WS_FEATB);
    __bf16* featT = (__bf16*)(ws + WS_FEATT);
    float*  Gpart = ws + WS_GPART;

    k_prep <<<NTILE32, 256, 0, stream>>>(feat, featB, featT, sPart);
    k_gram <<<dim3(10, NCHUNK), 256, 0, stream>>>(featB, Gpart);
    k_mid  <<<256, 256, 0, stream>>>(Gpart, sPart, Wi, bi, Wj, bj, Pt, q);
    k_final<<<dim3(NTILE32, 2), 256, 0, stream>>>(featT, Pt, q, out);
}